// Round 1
// baseline (5315.192 us; speedup 1.0000x reference)
//
#include <hip/hip_runtime.h>
#include <cstdint>
#include <cstddef>

#define T_SEQ 512
#define NB 32

// =====================================================================
// GEMM: C[M,N] = A[M,K] @ W[N,K]^T + (bi+bh)[N]
// Tile 64(M) x 128(N), K-chunk 32, 256 threads, 4x8 microtile.
// LDS stored transposed (As[k][m], Bs[k][n]) so fragments are float4 reads.
// =====================================================================
#define BM 64
#define BN 128
#define BK 32
#define AS_STRIDE 68   // pad: keeps ds_read_b128 16B-aligned, <=2-way banks
#define BS_STRIDE 132

__global__ __launch_bounds__(256, 4) void gemm_xp(
    const float* __restrict__ A, const float* __restrict__ W,
    const float* __restrict__ bi, const float* __restrict__ bh,
    float* __restrict__ C, int M, int N, int K)
{
    __shared__ float As[BK][AS_STRIDE];
    __shared__ float Bs[BK][BS_STRIDE];

    const int tid = threadIdx.x;
    const int tx = tid & 15;        // m group: 4 rows each -> 64
    const int ty = tid >> 4;        // n group: 8 cols each -> 128
    const int m0 = blockIdx.x * BM;
    const int n0 = blockIdx.y * BN;
    const int lr = tid >> 3;        // 0..31 row-in-pass
    const int lc = (tid & 7) << 2;  // k offset (float4)

    float acc[4][8];
#pragma unroll
    for (int i = 0; i < 4; i++)
#pragma unroll
        for (int j = 0; j < 8; j++) acc[i][j] = 0.f;

    for (int k0 = 0; k0 < K; k0 += BK) {
        // stage A tile (64 rows x 32 k), transposed into As[k][m]
#pragma unroll
        for (int p = 0; p < 2; p++) {
            const int m = p * 32 + lr;
            const float4 a4 = *(const float4*)(A + (size_t)(m0 + m) * K + k0 + lc);
            As[lc + 0][m] = a4.x; As[lc + 1][m] = a4.y;
            As[lc + 2][m] = a4.z; As[lc + 3][m] = a4.w;
        }
        // stage W tile (128 rows x 32 k), transposed into Bs[k][n]
#pragma unroll
        for (int p = 0; p < 4; p++) {
            const int n = p * 32 + lr;
            const float4 b4 = *(const float4*)(W + (size_t)(n0 + n) * K + k0 + lc);
            Bs[lc + 0][n] = b4.x; Bs[lc + 1][n] = b4.y;
            Bs[lc + 2][n] = b4.z; Bs[lc + 3][n] = b4.w;
        }
        __syncthreads();

#pragma unroll
        for (int kk = 0; kk < BK; kk++) {
            const float4 a4  = *(const float4*)&As[kk][tx << 2];
            const float4 b4a = *(const float4*)&Bs[kk][ty << 3];
            const float4 b4b = *(const float4*)&Bs[kk][(ty << 3) + 4];
            const float a[4] = { a4.x, a4.y, a4.z, a4.w };
            const float b[8] = { b4a.x, b4a.y, b4a.z, b4a.w,
                                 b4b.x, b4b.y, b4b.z, b4b.w };
#pragma unroll
            for (int i = 0; i < 4; i++)
#pragma unroll
                for (int j = 0; j < 8; j++)
                    acc[i][j] = fmaf(a[i], b[j], acc[i][j]);
        }
        __syncthreads();
    }

    // epilogue: + (b_ih + b_hh)
    const int nbase = n0 + (ty << 3);
    const float4 bia = *(const float4*)(bi + nbase);
    const float4 bib = *(const float4*)(bi + nbase + 4);
    const float4 bha = *(const float4*)(bh + nbase);
    const float4 bhb = *(const float4*)(bh + nbase + 4);
    const float bt[8] = { bia.x + bha.x, bia.y + bha.y, bia.z + bha.z, bia.w + bha.w,
                          bib.x + bhb.x, bib.y + bhb.y, bib.z + bhb.z, bib.w + bhb.w };
#pragma unroll
    for (int i = 0; i < 4; i++) {
        const int row = m0 + (tx << 2) + i;
        float4 o1, o2;
        o1.x = acc[i][0] + bt[0]; o1.y = acc[i][1] + bt[1];
        o1.z = acc[i][2] + bt[2]; o1.w = acc[i][3] + bt[3];
        o2.x = acc[i][4] + bt[4]; o2.y = acc[i][5] + bt[5];
        o2.z = acc[i][6] + bt[6]; o2.w = acc[i][7] + bt[7];
        *(float4*)(C + (size_t)row * N + nbase)     = o1;
        *(float4*)(C + (size_t)row * N + nbase + 4) = o2;
    }
}

// =====================================================================
// Recurrence helpers: cross-XCD visible loads/stores (agent scope)
// =====================================================================
__device__ __forceinline__ float agent_loadf(const float* p) {
    return __hip_atomic_load(p, __ATOMIC_RELAXED, __HIP_MEMORY_SCOPE_AGENT);
}
__device__ __forceinline__ void agent_storef(float* p, float v) {
    __hip_atomic_store(p, v, __ATOMIC_RELAXED, __HIP_MEMORY_SCOPE_AGENT);
}

// =====================================================================
// Recurrence, H=512 layers (0 and 1).
// 128 blocks = 32 batches x 4 row-slices. 512 threads/block.
// Each thread holds 128 fp32 of W_hh in VGPRs:
//   thread (jl, kq): W_hh[s*128 + jl][kq*128 .. kq*128+127]
// Per step: 128 FMA vs LDS-broadcast h, 4-way LDS reduce, tanh,
// publish slice via agent stores + release flag; spin-acquire other 3.
// Writes relu(h) in-place over xp (same element it read) for next layer.
// =====================================================================
__global__ __launch_bounds__(512, 2) void rec_h512(
    const float* __restrict__ Whh,   // [512,512]
    float* __restrict__ xpseq,       // [NB, T, 512]  in: xp, out: relu(h)
    float* __restrict__ h_buf,       // [2][NB][512]
    int* __restrict__ flags)         // [NB][4], pre-zeroed
{
    const int tid = threadIdx.x;
    const int b  = blockIdx.x >> 2;
    const int s  = blockIdx.x & 3;
    const int jl = tid & 127;
    const int j  = (s << 7) + jl;
    const int kq = tid >> 7;         // uniform within a wave -> broadcast reads

    __shared__ float h_lds[512];
    __shared__ float part[4][128];

    float w[128];
    {
        const float4* wp = (const float4*)(Whh + (size_t)j * 512 + (kq << 7));
#pragma unroll
        for (int i = 0; i < 32; i++) {
            const float4 v = wp[i];
            w[4 * i + 0] = v.x; w[4 * i + 1] = v.y;
            w[4 * i + 2] = v.z; w[4 * i + 3] = v.w;
        }
    }

    int* myflags = flags + (b << 2);
    float* xp_b = xpseq + (size_t)b * (T_SEQ * 512);

    for (int t = 0; t < T_SEQ; t++) {
        float a0 = 0.f, a1 = 0.f, a2 = 0.f, a3 = 0.f;
        if (t > 0) {
            if (tid < 4) {
                while (__hip_atomic_load(myflags + tid, __ATOMIC_ACQUIRE,
                                         __HIP_MEMORY_SCOPE_AGENT) < t)
                    __builtin_amdgcn_s_sleep(1);
            }
            __syncthreads();
            h_lds[tid] = agent_loadf(h_buf + ((size_t)(((t - 1) & 1) * NB + b)) * 512 + tid);
            __syncthreads();
            const float4* hp = (const float4*)(h_lds + (kq << 7));
#pragma unroll
            for (int i = 0; i < 32; i++) {
                const float4 h4 = hp[i];
                a0 = fmaf(w[4 * i + 0], h4.x, a0);
                a1 = fmaf(w[4 * i + 1], h4.y, a1);
                a2 = fmaf(w[4 * i + 2], h4.z, a2);
                a3 = fmaf(w[4 * i + 3], h4.w, a3);
            }
        }
        part[kq][jl] = (a0 + a1) + (a2 + a3);
        __syncthreads();
        if (tid < 128) {
            const int jj = (s << 7) + tid;
            const float v = part[0][tid] + part[1][tid] + part[2][tid] + part[3][tid]
                          + xp_b[t * 512 + jj];
            const float h = tanhf(v);
            agent_storef(h_buf + ((size_t)((t & 1) * NB + b)) * 512 + jj, h);
            xp_b[t * 512 + jj] = fmaxf(h, 0.f);   // relu'd sequence for next layer
        }
        __syncthreads();  // drains vmcnt per-wave: all slice stores complete
        if (tid == 0)
            __hip_atomic_store(myflags + s, t + 1, __ATOMIC_RELEASE,
                               __HIP_MEMORY_SCOPE_AGENT);
    }
}

// =====================================================================
// Recurrence, H=128 (layer 2). One WG per batch element; LDS-only sync.
// 256 threads: thread (j, kh) holds W_hh2[j][kh*64 .. kh*64+63] (64 VGPRs).
// Writes raw h to out and final h to hn.
// =====================================================================
__global__ __launch_bounds__(256, 4) void rec_h128(
    const float* __restrict__ Whh,   // [128,128]
    const float* __restrict__ xp,    // [NB, T, 128]
    float* __restrict__ out,         // [NB, T, 128]
    float* __restrict__ hn)          // [NB, 128]
{
    const int tid = threadIdx.x;
    const int b  = blockIdx.x;
    const int j  = tid & 127;
    const int kh = tid >> 7;

    __shared__ float h_lds[128];
    __shared__ float part[2][128];

    float w[64];
    {
        const float4* wp = (const float4*)(Whh + (size_t)j * 128 + (kh << 6));
#pragma unroll
        for (int i = 0; i < 16; i++) {
            const float4 v = wp[i];
            w[4 * i + 0] = v.x; w[4 * i + 1] = v.y;
            w[4 * i + 2] = v.z; w[4 * i + 3] = v.w;
        }
    }

    const float* xp_b = xp + (size_t)b * (T_SEQ * 128);
    float* out_b = out + (size_t)b * (T_SEQ * 128);

    for (int t = 0; t < T_SEQ; t++) {
        float a0 = 0.f, a1 = 0.f, a2 = 0.f, a3 = 0.f;
        if (t > 0) {
            const float4* hp = (const float4*)(h_lds + (kh << 6));
#pragma unroll
            for (int i = 0; i < 16; i++) {
                const float4 h4 = hp[i];
                a0 = fmaf(w[4 * i + 0], h4.x, a0);
                a1 = fmaf(w[4 * i + 1], h4.y, a1);
                a2 = fmaf(w[4 * i + 2], h4.z, a2);
                a3 = fmaf(w[4 * i + 3], h4.w, a3);
            }
        }
        part[kh][j] = (a0 + a1) + (a2 + a3);
        __syncthreads();
        if (tid < 128) {
            const float v = part[0][tid] + part[1][tid] + xp_b[t * 128 + tid];
            const float h = tanhf(v);
            h_lds[tid] = h;
            out_b[t * 128 + tid] = h;            // final layer: no relu
            if (t == T_SEQ - 1) hn[b * 128 + tid] = h;
        }
        __syncthreads();
    }
}

// =====================================================================
// Launch
// =====================================================================
extern "C" void kernel_launch(void* const* d_in, const int* in_sizes, int n_in,
                              void* d_out, int out_size, void* d_ws, size_t ws_size,
                              hipStream_t stream)
{
    const float* x    = (const float*)d_in[0];
    const float* Wih0 = (const float*)d_in[1];
    const float* Whh0 = (const float*)d_in[2];
    const float* bih0 = (const float*)d_in[3];
    const float* bhh0 = (const float*)d_in[4];
    const float* Wih1 = (const float*)d_in[5];
    const float* Whh1 = (const float*)d_in[6];
    const float* bih1 = (const float*)d_in[7];
    const float* bhh1 = (const float*)d_in[8];
    const float* Wih2 = (const float*)d_in[9];
    const float* Whh2 = (const float*)d_in[10];
    const float* bih2 = (const float*)d_in[11];
    const float* bhh2 = (const float*)d_in[12];

    float* ws   = (float*)d_ws;
    float* buf0 = ws;                      // xp0 -> relu(seq0), 8388608 f
    float* buf1 = ws + 8388608;            // xp1 -> relu(seq1), 8388608 f
    float* xp2  = ws + 16777216;           // 2097152 f
    float* hbuf = ws + 18874368;           // 2*32*512 = 32768 f
    int*   flg  = (int*)(ws + 18907136);   // 2 layers x 128 ints

    float* out = (float*)d_out;            // [32,512,128]
    float* hn  = out + NB * T_SEQ * 128;   // [1,32,128]

    hipMemsetAsync(flg, 0, 256 * sizeof(int), stream);

    const int M = NB * T_SEQ;  // 16384

    // layer 0
    gemm_xp<<<dim3(M / BM, 512 / BN), 256, 0, stream>>>(x, Wih0, bih0, bhh0, buf0, M, 512, 128);
    rec_h512<<<NB * 4, 512, 0, stream>>>(Whh0, buf0, hbuf, flg);
    // layer 1
    gemm_xp<<<dim3(M / BM, 512 / BN), 256, 0, stream>>>(buf0, Wih1, bih1, bhh1, buf1, M, 512, 512);
    rec_h512<<<NB * 4, 512, 0, stream>>>(Whh1, buf1, hbuf, flg + 128);
    // layer 2
    gemm_xp<<<dim3(M / BM, 128 / BN), 256, 0, stream>>>(buf1, Wih2, bih2, bhh2, xp2, M, 128, 512);
    rec_h128<<<NB, 256, 0, stream>>>(Whh2, xp2, out, hn);
}

// Round 2
// 2261.756 us; speedup vs baseline: 2.3500x; 2.3500x over previous
//
#include <hip/hip_runtime.h>
#include <hip/hip_fp16.h>
#include <cstdint>
#include <cstddef>
#include <cstring>

#define T_SEQ 512
#define NB 32

// =====================================================================
// GEMM: C[M,N] = A[M,K] @ W[N,K]^T + (bi+bh)[N]
// Tile 64(M) x 128(N), K-chunk 32, 256 threads, 4x8 microtile.
// =====================================================================
#define BM 64
#define BN 128
#define BK 32
#define AS_STRIDE 68
#define BS_STRIDE 132

__global__ __launch_bounds__(256, 4) void gemm_xp(
    const float* __restrict__ A, const float* __restrict__ W,
    const float* __restrict__ bi, const float* __restrict__ bh,
    float* __restrict__ C, int M, int N, int K)
{
    __shared__ float As[BK][AS_STRIDE];
    __shared__ float Bs[BK][BS_STRIDE];

    const int tid = threadIdx.x;
    const int tx = tid & 15;
    const int ty = tid >> 4;
    const int m0 = blockIdx.x * BM;
    const int n0 = blockIdx.y * BN;
    const int lr = tid >> 3;
    const int lc = (tid & 7) << 2;

    float acc[4][8];
#pragma unroll
    for (int i = 0; i < 4; i++)
#pragma unroll
        for (int j = 0; j < 8; j++) acc[i][j] = 0.f;

    for (int k0 = 0; k0 < K; k0 += BK) {
#pragma unroll
        for (int p = 0; p < 2; p++) {
            const int m = p * 32 + lr;
            const float4 a4 = *(const float4*)(A + (size_t)(m0 + m) * K + k0 + lc);
            As[lc + 0][m] = a4.x; As[lc + 1][m] = a4.y;
            As[lc + 2][m] = a4.z; As[lc + 3][m] = a4.w;
        }
#pragma unroll
        for (int p = 0; p < 4; p++) {
            const int n = p * 32 + lr;
            const float4 b4 = *(const float4*)(W + (size_t)(n0 + n) * K + k0 + lc);
            Bs[lc + 0][n] = b4.x; Bs[lc + 1][n] = b4.y;
            Bs[lc + 2][n] = b4.z; Bs[lc + 3][n] = b4.w;
        }
        __syncthreads();

#pragma unroll
        for (int kk = 0; kk < BK; kk++) {
            const float4 a4  = *(const float4*)&As[kk][tx << 2];
            const float4 b4a = *(const float4*)&Bs[kk][ty << 3];
            const float4 b4b = *(const float4*)&Bs[kk][(ty << 3) + 4];
            const float a[4] = { a4.x, a4.y, a4.z, a4.w };
            const float b[8] = { b4a.x, b4a.y, b4a.z, b4a.w,
                                 b4b.x, b4b.y, b4b.z, b4b.w };
#pragma unroll
            for (int i = 0; i < 4; i++)
#pragma unroll
                for (int j = 0; j < 8; j++)
                    acc[i][j] = fmaf(a[i], b[j], acc[i][j]);
        }
        __syncthreads();
    }

    const int nbase = n0 + (ty << 3);
    const float4 bia = *(const float4*)(bi + nbase);
    const float4 bib = *(const float4*)(bi + nbase + 4);
    const float4 bha = *(const float4*)(bh + nbase);
    const float4 bhb = *(const float4*)(bh + nbase + 4);
    const float bt[8] = { bia.x + bha.x, bia.y + bha.y, bia.z + bha.z, bia.w + bha.w,
                          bib.x + bhb.x, bib.y + bhb.y, bib.z + bhb.z, bib.w + bhb.w };
#pragma unroll
    for (int i = 0; i < 4; i++) {
        const int row = m0 + (tx << 2) + i;
        float4 o1, o2;
        o1.x = acc[i][0] + bt[0]; o1.y = acc[i][1] + bt[1];
        o1.z = acc[i][2] + bt[2]; o1.w = acc[i][3] + bt[3];
        o2.x = acc[i][4] + bt[4]; o2.y = acc[i][5] + bt[5];
        o2.z = acc[i][6] + bt[6]; o2.w = acc[i][7] + bt[7];
        *(float4*)(C + (size_t)row * N + nbase)     = o1;
        *(float4*)(C + (size_t)row * N + nbase + 4) = o2;
    }
}

// =====================================================================
// Recurrence, H=512 (layers 0,1).
// Grid: 128 blocks, block = s*32 + b  (s = row-slice, b = batch).
// 512 threads: (jl = tid&127, kq = tid>>7). Thread holds
// W_hh[s*128+jl][kq*128 .. +127] in 128 regs.
//
// Cross-WG h exchange: ONE self-validating packed word per element:
//   uint32 = (fp16(h) << 16) | tag,  tag = tagbase + t + 1.
// Consumer spins on the word itself (relaxed agent load) — single LLC
// round trip, no flags, no fences. Own slice short-circuits via LDS.
// Workspace is poisoned 0xAA -> tag field 0xAAAA never matches [1,1536].
// 2 barriers per step. xp[t+1] prefetched one iteration ahead.
// =====================================================================
__global__ __launch_bounds__(512, 2) void rec_h512(
    const float* __restrict__ Whh,   // [512,512]
    float* __restrict__ xpseq,       // [NB, T, 512] in: xp, out: relu(h)
    uint32_t* __restrict__ hpk,      // [NB][512] packed h words
    int tagbase)
{
    const int tid = threadIdx.x;
    const int b  = blockIdx.x & 31;
    const int s  = blockIdx.x >> 5;
    const int jl = tid & 127;
    const int kq = tid >> 7;         // wave-uniform
    const bool own = (kq == s);

    __shared__ float hbuf[2][512];
    __shared__ float part[4][128];

    float w[128];
    {
        const float4* wp = (const float4*)(Whh + (size_t)((s << 7) + jl) * 512 + (kq << 7));
#pragma unroll
        for (int i = 0; i < 32; i++) {
            const float4 v = wp[i];
            w[4 * i + 0] = v.x; w[4 * i + 1] = v.y;
            w[4 * i + 2] = v.z; w[4 * i + 3] = v.w;
        }
    }

    uint32_t* hp_b = hpk + b * 512;
    float* xp_b = xpseq + (size_t)b * (T_SEQ * 512);
    const int myrow = (s << 7) + tid;            // publisher row (tid<128)

    float xpv = (tid < 128) ? xp_b[myrow] : 0.f; // xp[0][myrow]

    for (int t = 0; t < T_SEQ; t++) {
        const int p = t & 1;
        // prefetch next xp off the critical path
        float xpn = (tid < 128 && t + 1 < T_SEQ) ? xp_b[(t + 1) * 512 + myrow] : 0.f;

        float a0 = 0.f, a1 = 0.f, a2 = 0.f, a3 = 0.f;
        if (t > 0) {
            if (!own) {
                const uint32_t wtag = (uint32_t)(tagbase + t);
                uint32_t v;
                do {
                    v = __hip_atomic_load(hp_b + tid, __ATOMIC_RELAXED,
                                          __HIP_MEMORY_SCOPE_AGENT);
                } while ((v & 0xffffu) != wtag);
                const unsigned short us = (unsigned short)(v >> 16);
                __half hh; __builtin_memcpy(&hh, &us, 2);
                hbuf[p][tid] = __half2float(hh);
            }
            __syncthreads();   // decode complete (also orders publisher LDS writes)
            const float4* hq = (const float4*)(&hbuf[p][kq << 7]);
#pragma unroll
            for (int i = 0; i < 32; i++) {
                const float4 h4 = hq[i];
                a0 = fmaf(w[4 * i + 0], h4.x, a0);
                a1 = fmaf(w[4 * i + 1], h4.y, a1);
                a2 = fmaf(w[4 * i + 2], h4.z, a2);
                a3 = fmaf(w[4 * i + 3], h4.w, a3);
            }
        }
        part[kq][jl] = (a0 + a1) + (a2 + a3);
        __syncthreads();       // parts ready
        if (tid < 128) {
            const float v = part[0][tid] + part[1][tid] + part[2][tid] + part[3][tid] + xpv;
            const float h = tanhf(v);
            // publish FIRST (single self-validating word, fire-and-forget)
            __half hh = __float2half_rn(h);
            unsigned short us; __builtin_memcpy(&us, &hh, 2);
            const uint32_t pkv = ((uint32_t)us << 16) | (uint32_t)(tagbase + t + 1);
            __hip_atomic_store(hp_b + myrow, pkv, __ATOMIC_RELAXED,
                               __HIP_MEMORY_SCOPE_AGENT);
            hbuf[(t + 1) & 1][myrow] = h;        // own-slice fast path (fp32)
            xp_b[t * 512 + myrow] = fmaxf(h, 0.f);
        }
        // no trailing barrier: next step's decode barrier orders part[] reuse
        xpv = xpn;
    }
}

// =====================================================================
// Recurrence, H=128 (layer 2). One WG per batch; LDS-only, 2 barriers.
// =====================================================================
__global__ __launch_bounds__(256, 4) void rec_h128(
    const float* __restrict__ Whh,   // [128,128]
    const float* __restrict__ xp,    // [NB, T, 128]
    float* __restrict__ out,         // [NB, T, 128]
    float* __restrict__ hn)          // [NB, 128]
{
    const int tid = threadIdx.x;
    const int b  = blockIdx.x;
    const int j  = tid & 127;
    const int kh = tid >> 7;

    __shared__ float hbuf[2][128];
    __shared__ float part[2][128];

    float w[64];
    {
        const float4* wp = (const float4*)(Whh + (size_t)j * 128 + (kh << 6));
#pragma unroll
        for (int i = 0; i < 16; i++) {
            const float4 v = wp[i];
            w[4 * i + 0] = v.x; w[4 * i + 1] = v.y;
            w[4 * i + 2] = v.z; w[4 * i + 3] = v.w;
        }
    }

    const float* xp_b = xp + (size_t)b * (T_SEQ * 128);
    float* out_b = out + (size_t)b * (T_SEQ * 128);

    float xpv = (tid < 128) ? xp_b[tid] : 0.f;

    for (int t = 0; t < T_SEQ; t++) {
        float xpn = (tid < 128 && t + 1 < T_SEQ) ? xp_b[(t + 1) * 128 + tid] : 0.f;

        float a0 = 0.f, a1 = 0.f, a2 = 0.f, a3 = 0.f;
        if (t > 0) {
            const float4* hq = (const float4*)(&hbuf[t & 1][kh << 6]);
#pragma unroll
            for (int i = 0; i < 16; i++) {
                const float4 h4 = hq[i];
                a0 = fmaf(w[4 * i + 0], h4.x, a0);
                a1 = fmaf(w[4 * i + 1], h4.y, a1);
                a2 = fmaf(w[4 * i + 2], h4.z, a2);
                a3 = fmaf(w[4 * i + 3], h4.w, a3);
            }
        }
        part[kh][j] = (a0 + a1) + (a2 + a3);
        __syncthreads();
        if (tid < 128) {
            const float v = part[0][tid] + part[1][tid] + xpv;
            const float h = tanhf(v);
            hbuf[(t + 1) & 1][tid] = h;
            out_b[t * 128 + tid] = h;
            if (t == T_SEQ - 1) hn[b * 128 + tid] = h;
        }
        __syncthreads();
        xpv = xpn;
    }
}

// =====================================================================
// Launch
// =====================================================================
extern "C" void kernel_launch(void* const* d_in, const int* in_sizes, int n_in,
                              void* d_out, int out_size, void* d_ws, size_t ws_size,
                              hipStream_t stream)
{
    const float* x    = (const float*)d_in[0];
    const float* Wih0 = (const float*)d_in[1];
    const float* Whh0 = (const float*)d_in[2];
    const float* bih0 = (const float*)d_in[3];
    const float* bhh0 = (const float*)d_in[4];
    const float* Wih1 = (const float*)d_in[5];
    const float* Whh1 = (const float*)d_in[6];
    const float* bih1 = (const float*)d_in[7];
    const float* bhh1 = (const float*)d_in[8];
    const float* Wih2 = (const float*)d_in[9];
    const float* Whh2 = (const float*)d_in[10];
    const float* bih2 = (const float*)d_in[11];
    const float* bhh2 = (const float*)d_in[12];

    float* ws   = (float*)d_ws;
    float* buf0 = ws;                      // xp0 -> relu(seq0), 8388608 f
    float* buf1 = ws + 8388608;            // xp1 -> relu(seq1), 8388608 f
    float* xp2  = ws + 16777216;           // 2097152 f
    uint32_t* hpk = (uint32_t*)(ws + 18874368);  // [32][512] packed h

    float* out = (float*)d_out;            // [32,512,128]
    float* hn  = out + NB * T_SEQ * 128;   // [1,32,128]

    const int M = NB * T_SEQ;  // 16384

    // layer 0
    gemm_xp<<<dim3(M / BM, 512 / BN), 256, 0, stream>>>(x, Wih0, bih0, bhh0, buf0, M, 512, 128);
    rec_h512<<<NB * 4, 512, 0, stream>>>(Whh0, buf0, hpk, 0);
    // layer 1
    gemm_xp<<<dim3(M / BM, 512 / BN), 256, 0, stream>>>(buf0, Wih1, bih1, bhh1, buf1, M, 512, 512);
    rec_h512<<<NB * 4, 512, 0, stream>>>(Whh1, buf1, hpk, 1024);
    // layer 2
    gemm_xp<<<dim3(M / BM, 128 / BN), 256, 0, stream>>>(buf1, Wih2, bih2, bhh2, xp2, M, 128, 512);
    rec_h128<<<NB, 256, 0, stream>>>(Whh2, xp2, out, hn);
}